// Round 8
// baseline (2197.556 us; speedup 1.0000x reference)
//
#include <hip/hip_runtime.h>
#include <cstddef>

#define TSEQ 48
#define TDEC 60

typedef float v2f __attribute__((ext_vector_type(2)));
typedef float v4f __attribute__((ext_vector_type(4)));

__device__ __forceinline__ float rcpf(float x){ return __builtin_amdgcn_rcpf(x); }
__device__ __forceinline__ float sigm(float x){ return rcpf(1.0f + __expf(-x)); }
__device__ __forceinline__ float tanhx(float x){ return 1.0f - 2.0f*rcpf(__expf(2.0f*x) + 1.0f); }

__device__ __forceinline__ v2f pkfma(v2f a, v2f b, v2f c){ return __builtin_elementwise_fma(a, b, c); }
#define SVLO(v) __builtin_shufflevector((v),(v),0,1)
#define SVHI(v) __builtin_shufflevector((v),(v),2,3)

// DPP lane exchange: 1 VALU inst, no LDS-pipe latency (vs ds_bpermute ~30cyc).
// quad_perm: xor1=0xB1 (1,0,3,2), xor2=0x4E (2,3,0,1), xor3=0x1B (3,2,1,0).
// row_ror:8 = 0x128: (i+8)%16 == i^8 within each 16-lane row -> exact xor8.
template<int CTRL>
__device__ __forceinline__ float dppf(float x){
    return __int_as_float(__builtin_amdgcn_mov_dpp(__float_as_int(x), CTRL, 0xF, 0xF, true));
}

// 32 floats (8 aligned v4f) -> 16 packed pairs. Works for LDS or global ptrs.
__device__ __forceinline__ void load_pairs32(const float* p, v2f o[16]){
    #pragma unroll
    for (int q=0;q<8;++q){
        v4f v = *(const v4f*)(p + 4*q);
        o[2*q]   = SVLO(v);
        o[2*q+1] = SVHI(v);
    }
}

// R8 (on R7's 8-elem/wave structure):
//  - __launch_bounds__(256,4): R7 showed ~1.7 waves/SIMD residency with VGPR=124
//    (fits 4/SIMD). Hypothesis: waves-per-eu=2 metadata capped residency.
//    VGPR budget at min-waves=4 is 128; we fit (canary: FETCH_SIZE ~25MB).
//  - DPP replaces xor1/2/3 (quad_perm) and xor8 (row_ror:8) shuffles:
//    ~25 fewer DS ops + serial-latency links per t-step.
__global__ __launch_bounds__(256, 4)
void lstm_fused(const float* __restrict__ x,
                const float* __restrict__ w1i, const float* __restrict__ w1h, const float* __restrict__ b1,
                const float* __restrict__ w2i, const float* __restrict__ w2h, const float* __restrict__ b2,
                const float* __restrict__ w3i, const float* __restrict__ w3h, const float* __restrict__ b3,
                const float* __restrict__ w4i, const float* __restrict__ w4h, const float* __restrict__ b4,
                const float* __restrict__ w5i, const float* __restrict__ w5h, const float* __restrict__ b5,
                const float* __restrict__ w6i, const float* __restrict__ w6h, const float* __restrict__ b6,
                const float* __restrict__ fc1w, const float* __restrict__ fc1b,
                const float* __restrict__ fc2w, const float* __restrict__ fc2b,
                float* __restrict__ out)
{
    const int lane  = threadIdx.x & 63;
    const int w     = threadIdx.x >> 6;     // wave in block (0..3)
    const int g8    = lane >> 3;            // 8-elem sub-index (0..7)
    const int r8    = lane & 7;
    const int base8 = lane & 56;            // 8-lane group base
    const int g16   = lane >> 4;            // epilogue 16-lane grouping
    const int r16   = lane & 15;
    const int eb0   = w * 8;                // first block-elem of this wave
    const int ebg8  = eb0 + g8;
    const long gelem0 = (long)blockIdx.x * 32 + eb0;

    // per-wave-owned LDS (block-elem 0..31) -> no __syncthreads
    __shared__ float h1s[32][32];
    __shared__ float h2s[32][8];
    __shared__ float h6s[32][68];
    __shared__ float accs[32][36];

    #pragma unroll
    for (int e=0;e<8;++e){
        if (lane<32) h1s[eb0+e][lane]=0.f;
        if (lane<8)  h2s[eb0+e][lane]=0.f;
    }

    // ---------------- weight preload (packed-pair, register-resident) ----
    // e1: even lane holds rows {i_u, g_u}; odd lane {f_u, o_u}; u=lane>>1
    const int  u1  = lane >> 1;
    const int  rA  = ((lane & 1) << 5) + u1;
    const int  rB  = 64 + rA;
    const bool evn = (lane & 1) == 0;
    v2f w1iA2[4], w1iB2[4], w1hA2[16], w1hB2[16];
    {
        #pragma unroll
        for (int q=0;q<2;++q){
            v4f va = *(const v4f*)(w1i + rA*8 + 4*q);
            v4f vb = *(const v4f*)(w1i + rB*8 + 4*q);
            w1iA2[2*q]=SVLO(va); w1iA2[2*q+1]=SVHI(va);
            w1iB2[2*q]=SVLO(vb); w1iB2[2*q+1]=SVHI(vb);
        }
        load_pairs32(w1h + rA*32, w1hA2);
        load_pairs32(w1h + rB*32, w1hB2);
    }
    const float bA_ = b1[rA], bB_ = b1[rB];

    // e2: lane owns row r2 (halves serve different elems)
    const int r2 = lane & 31;
    v2f w2i2[16], w2h2[4];
    {
        load_pairs32(w2i + r2*32, w2i2);
        v4f v0 = *(const v4f*)(w2h + r2*8);
        v4f v1 = *(const v4f*)(w2h + r2*8 + 4);
        w2h2[0]=SVLO(v0); w2h2[1]=SVHI(v0); w2h2[2]=SVLO(v1); w2h2[3]=SVHI(v1);
    }
    const float b2_ = b2[r2];
    const bool tg2 = ((r2>>3)==2);

    // e3/d3 rows on r34 = r8&3 (duplicated in both 4-lane subgroups)
    const int r34 = r8 & 3;
    float w3i_[8];
    {
        const float4* p = (const float4*)(w3i + r34*8);
        float4 v0=p[0], v1=p[1];
        w3i_[0]=v0.x;w3i_[1]=v0.y;w3i_[2]=v0.z;w3i_[3]=v0.w;
        w3i_[4]=v1.x;w3i_[5]=v1.y;w3i_[6]=v1.z;w3i_[7]=v1.w;
    }
    const float w3h_ = w3h[r34], b3_ = b3[r34];
    const bool tg3 = (r34==2);

    // d1/d2 rows on r8 (8 rows x 8 elems = full wave)
    const float w4i_ = w4i[r8], w4h0 = w4h[r8*2], w4h1 = w4h[r8*2+1], b4_ = b4[r8];
    const float w5i0 = w5i[r8*2], w5i1 = w5i[r8*2+1], w5h0 = w5h[r8*2], w5h1 = w5h[r8*2+1], b5_ = b5[r8];
    const bool tg45 = ((r8>>1)==2);
    const float w6i0 = w6i[r34*2], w6i1 = w6i[r34*2+1], w6h_ = w6h[r34], b6_ = b6[r34];

    // ---------------- states -------------------------------------------
    float c1e[8] = {0.f,0.f,0.f,0.f,0.f,0.f,0.f,0.f};
    float c2p[4] = {0.f,0.f,0.f,0.f};
    float c3=0.f, h3=0.f;
    float c4=0.f, h4a=0.f, h4b=0.f;
    float c5=0.f, h5a=0.f, h5b=0.f;
    float c6=0.f, h6=0.f;

    // ================= encoder loop (t < 48) ===========================
    for (int t=0; t<TSEQ; ++t){
        // ---- e1: 8 passes, shared packed weights ----
        #pragma unroll
        for (int e=0;e<8;++e){
            const float* xr = x + (size_t)(gelem0+e)*(TSEQ*8) + t*8;
            v4f xa = *(const v4f*)xr;
            v4f xb = *(const v4f*)(xr+4);
            v2f xp[4] = { SVLO(xa), SVHI(xa), SVLO(xb), SVHI(xb) };
            v2f h1p[16];
            load_pairs32(&h1s[eb0+e][0], h1p);

            v2f aq[2] = { (v2f){bA_,0.f}, (v2f){0.f,0.f} };
            v2f bq[2] = { (v2f){bB_,0.f}, (v2f){0.f,0.f} };
            #pragma unroll
            for (int j=0;j<4;++j){
                aq[j&1] = pkfma(w1iA2[j], xp[j], aq[j&1]);
                bq[j&1] = pkfma(w1iB2[j], xp[j], bq[j&1]);
            }
            #pragma unroll
            for (int k=0;k<16;++k){
                aq[k&1] = pkfma(w1hA2[k], h1p[k], aq[k&1]);
                bq[k&1] = pkfma(w1hB2[k], h1p[k], bq[k&1]);
            }
            const v2f as = aq[0] + aq[1];
            const v2f bs = bq[0] + bq[1];
            const float gA = as[0] + as[1];
            const float gB = bs[0] + bs[1];

            const float actA = sigm(gA);                 // i (even) / f (odd)
            const float sB   = sigm(evn ? 2.f*gB : gB);
            const float actB = evn ? 2.f*sB-1.f : sB;    // tanh g / sigm o
            const float pA = dppf<0xB1>(actA);           // xor1 via quad_perm
            const float pB = dppf<0xB1>(actB);
            const float iv = evn ? actA : pA;
            const float fv = evn ? pA   : actA;
            const float gv = evn ? actB : pB;
            const float ov = evn ? pB   : actB;
            c1e[e] = fv*c1e[e] + iv*gv;
            const float h1n = ov*tanhx(c1e[e]);
            if (evn) h1s[eb0+e][u1] = h1n;
        }

        // ---- e2: 4 passes x 2 elems ----
        #pragma unroll
        for (int p=0;p<4;++p){
            const int eb2 = eb0 + p*2 + (lane>>5);
            v2f h1p[16];
            load_pairs32(&h1s[eb2][0], h1p);
            v2f h2p[4];
            {
                v4f v0 = *(const v4f*)&h2s[eb2][0];
                v4f v1 = *(const v4f*)&h2s[eb2][4];
                h2p[0]=SVLO(v0); h2p[1]=SVHI(v0); h2p[2]=SVLO(v1); h2p[3]=SVHI(v1);
            }
            v2f qq[2] = { (v2f){b2_,0.f}, (v2f){0.f,0.f} };
            #pragma unroll
            for (int k=0;k<16;++k) qq[k&1] = pkfma(w2i2[k], h1p[k], qq[k&1]);
            #pragma unroll
            for (int k=0;k<4;++k)  qq[k&1] = pkfma(w2h2[k], h2p[k], qq[k&1]);
            const v2f qs = qq[0] + qq[1];
            const float g2 = qs[0] + qs[1];

            const float s2 = sigm(tg2 ? 2.f*g2 : g2);
            const float a2 = tg2 ? 2.f*s2-1.f : s2;
            const float f2  = dppf<0x128>(a2);           // xor8 via row_ror:8
            const float gv2 = __shfl_xor(a2, 16);
            const float o2  = __shfl_xor(a2, 24);
            c2p[p] = f2*c2p[p] + a2*gv2;           // valid r2<8
            const float h2n = o2*tanhx(c2p[p]);
            if (r2<8) h2s[eb2][r2] = h2n;
        }

        // ---- e3: 8 elems in 8-lane groups (rows duplicated in 4-subgroups)
        float h2g[8];
        {
            v4f v0 = *(const v4f*)&h2s[ebg8][0];
            v4f v1 = *(const v4f*)&h2s[ebg8][4];
            h2g[0]=v0[0];h2g[1]=v0[1];h2g[2]=v0[2];h2g[3]=v0[3];
            h2g[4]=v1[0];h2g[5]=v1[1];h2g[6]=v1[2];h2g[7]=v1[3];
        }
        float g3 = b3_ + w3h_*h3;
        #pragma unroll
        for (int j=0;j<8;++j) g3 += w3i_[j]*h2g[j];
        const float s3 = sigm(tg3 ? 2.f*g3 : g3);
        const float a3 = tg3 ? 2.f*s3-1.f : s3;
        const float e1x = dppf<0xB1>(a3);            // xor1
        const float e2x = dppf<0x4E>(a3);            // xor2
        const float e3x = dppf<0x1B>(a3);            // xor3
        c3 = e1x*c3 + a3*e2x;                      // valid r34==0
        h3 = __shfl(e3x*tanhx(c3), base8);
        const float din = h3;

        // ---- d1/d2/d3 + h6 store ----
        {
            const float g = b4_ + w4i_*din + w4h0*h4a + w4h1*h4b;
            const float s = sigm(tg45 ? 2.f*g : g);
            const float a = tg45 ? 2.f*s-1.f : s;
            const float y2 = dppf<0x4E>(a);          // xor2
            const float y4 = __shfl_xor(a, 4);
            const float y6 = __shfl_xor(a, 6);
            c4 = y2*c4 + a*y4;                     // valid r8<2
            const float hl = y6*tanhx(c4);
            h4a = __shfl(hl, base8);
            h4b = __shfl(hl, base8+1);
        }
        {
            const float g = b5_ + w5i0*h4a + w5i1*h4b + w5h0*h5a + w5h1*h5b;
            const float s = sigm(tg45 ? 2.f*g : g);
            const float a = tg45 ? 2.f*s-1.f : s;
            const float y2 = dppf<0x4E>(a);
            const float y4 = __shfl_xor(a, 4);
            const float y6 = __shfl_xor(a, 6);
            c5 = y2*c5 + a*y4;
            const float hl = y6*tanhx(c5);
            h5a = __shfl(hl, base8);
            h5b = __shfl(hl, base8+1);
        }
        {
            const float g = b6_ + w6i0*h5a + w6i1*h5b + w6h_*h6;
            const float s = sigm(tg3 ? 2.f*g : g);
            const float a = tg3 ? 2.f*s-1.f : s;
            const float z1 = dppf<0xB1>(a);
            const float z2 = dppf<0x4E>(a);
            const float z3 = dppf<0x1B>(a);
            c6 = z1*c6 + a*z2;                     // valid r34==0
            h6 = __shfl(z3*tanhx(c6), base8);
        }
        if (r8==0) h6s[ebg8][t] = h6;
    }

    // ================= decoder-only loop (t >= 48) =====================
    for (int t=TSEQ; t<TDEC; ++t){
        const float din = x[(size_t)(gelem0+g8)*(TSEQ*8) + (t-12)*8 + 4];
        {
            const float g = b4_ + w4i_*din + w4h0*h4a + w4h1*h4b;
            const float s = sigm(tg45 ? 2.f*g : g);
            const float a = tg45 ? 2.f*s-1.f : s;
            const float y2 = dppf<0x4E>(a);
            const float y4 = __shfl_xor(a, 4);
            const float y6 = __shfl_xor(a, 6);
            c4 = y2*c4 + a*y4;
            const float hl = y6*tanhx(c4);
            h4a = __shfl(hl, base8);
            h4b = __shfl(hl, base8+1);
        }
        {
            const float g = b5_ + w5i0*h4a + w5i1*h4b + w5h0*h5a + w5h1*h5b;
            const float s = sigm(tg45 ? 2.f*g : g);
            const float a = tg45 ? 2.f*s-1.f : s;
            const float y2 = dppf<0x4E>(a);
            const float y4 = __shfl_xor(a, 4);
            const float y6 = __shfl_xor(a, 6);
            c5 = y2*c5 + a*y4;
            const float hl = y6*tanhx(c5);
            h5a = __shfl(hl, base8);
            h5b = __shfl(hl, base8+1);
        }
        {
            const float g = b6_ + w6i0*h5a + w6i1*h5b + w6h_*h6;
            const float s = sigm(tg3 ? 2.f*g : g);
            const float a = tg3 ? 2.f*s-1.f : s;
            const float z1 = dppf<0xB1>(a);
            const float z2 = dppf<0x4E>(a);
            const float z3 = dppf<0x1B>(a);
            c6 = z1*c6 + a*z2;
            h6 = __shfl(z3*tanhx(c6), base8);
        }
        if (r8==0) h6s[ebg8][t] = h6;
    }

    // ================= epilogue: fc1/fc2, two 4-elem passes ============
    #pragma unroll
    for (int p=0;p<2;++p){
        const int ebgE = eb0 + p*4 + g16;
        {
            float a0 = fc1b[r16], a1 = fc1b[16+r16];
            const float* f0 = fc1w + r16*60;
            const float* f1 = fc1w + (16+r16)*60;
            #pragma unroll
            for (int q=0;q<15;++q){
                float4 hv = *reinterpret_cast<float4*>(&h6s[ebgE][4*q]);
                float4 u0 = *reinterpret_cast<const float4*>(f0 + 4*q);
                float4 u1v= *reinterpret_cast<const float4*>(f1 + 4*q);
                a0 += u0.x*hv.x + u0.y*hv.y + u0.z*hv.z + u0.w*hv.w;
                a1 += u1v.x*hv.x + u1v.y*hv.y + u1v.z*hv.z + u1v.w*hv.w;
            }
            accs[ebgE][r16]    = a0;
            accs[ebgE][16+r16] = a1;
        }
        if (r16 < 12){
            float o = fc2b[r16];
            const float* fr = fc2w + r16*32;
            #pragma unroll
            for (int q=0;q<8;++q){
                float4 av = *reinterpret_cast<float4*>(&accs[ebgE][4*q]);
                float4 wv = *reinterpret_cast<const float4*>(fr + 4*q);
                o += wv.x*av.x + wv.y*av.y + wv.z*av.z + wv.w*av.w;
            }
            out[(size_t)(gelem0 + p*4 + g16)*12 + r16] = o;
        }
    }
}

extern "C" void kernel_launch(void* const* d_in, const int* in_sizes, int n_in,
                              void* d_out, int out_size, void* d_ws, size_t ws_size,
                              hipStream_t stream)
{
    const float* x    = (const float*)d_in[0];
    const float* w1i  = (const float*)d_in[1];
    const float* w1h  = (const float*)d_in[2];
    const float* b1   = (const float*)d_in[3];
    const float* w2i  = (const float*)d_in[4];
    const float* w2h  = (const float*)d_in[5];
    const float* b2   = (const float*)d_in[6];
    const float* w3i  = (const float*)d_in[7];
    const float* w3h  = (const float*)d_in[8];
    const float* b3   = (const float*)d_in[9];
    const float* w4i  = (const float*)d_in[10];
    const float* w4h  = (const float*)d_in[11];
    const float* b4   = (const float*)d_in[12];
    const float* w5i  = (const float*)d_in[13];
    const float* w5h  = (const float*)d_in[14];
    const float* b5   = (const float*)d_in[15];
    const float* w6i  = (const float*)d_in[16];
    const float* w6h  = (const float*)d_in[17];
    const float* b6   = (const float*)d_in[18];
    const float* fc1w = (const float*)d_in[19];
    const float* fc1b = (const float*)d_in[20];
    const float* fc2w = (const float*)d_in[21];
    const float* fc2b = (const float*)d_in[22];

    // 8 elems/wave, 4 waves/block -> 32 elems/block -> 1024 blocks
    lstm_fused<<<dim3(32768/32), dim3(256), 0, stream>>>(
        x, w1i,w1h,b1, w2i,w2h,b2, w3i,w3h,b3,
        w4i,w4h,b4, w5i,w5h,b5, w6i,w6h,b6,
        fc1w,fc1b, fc2w,fc2b, (float*)d_out);
}

// Round 9
// 598.553 us; speedup vs baseline: 3.6715x; 3.6715x over previous
//
#include <hip/hip_runtime.h>
#include <cstddef>

#define TSEQ 48
#define TDEC 60

typedef float v2f __attribute__((ext_vector_type(2)));
typedef float v4f __attribute__((ext_vector_type(4)));

__device__ __forceinline__ float rcpf(float x){ return __builtin_amdgcn_rcpf(x); }
__device__ __forceinline__ float sigm(float x){ return rcpf(1.0f + __expf(-x)); }
__device__ __forceinline__ float tanhx(float x){ return 1.0f - 2.0f*rcpf(__expf(2.0f*x) + 1.0f); }

__device__ __forceinline__ v2f pkfma(v2f a, v2f b, v2f c){ return __builtin_elementwise_fma(a, b, c); }
#define SVLO(v) __builtin_shufflevector((v),(v),0,1)
#define SVHI(v) __builtin_shufflevector((v),(v),2,3)

// DPP lane exchange: 1 VALU inst, no LDS-pipe latency (vs ds_bpermute ~30cyc).
// quad_perm: xor1=0xB1 (1,0,3,2), xor2=0x4E (2,3,0,1), xor3=0x1B (3,2,1,0).
// row_ror:8 = 0x128: (i+8)%16 == i^8 within each 16-lane row -> exact xor8.
template<int CTRL>
__device__ __forceinline__ float dppf(float x){
    return __int_as_float(__builtin_amdgcn_mov_dpp(__float_as_int(x), CTRL, 0xF, 0xF, true));
}

// 32 floats (8 aligned v4f) -> 16 packed pairs. Works for LDS or global ptrs.
__device__ __forceinline__ void load_pairs32(const float* p, v2f o[16]){
    #pragma unroll
    for (int q=0;q<8;++q){
        v4f v = *(const v4f*)(p + 4*q);
        o[2*q]   = SVLO(v);
        o[2*q+1] = SVHI(v);
    }
}

// R9 = R7 structure (8 elems/wave) + DPP shuffles, launch_bounds REVERTED to
// (256,2). Twice-proven rule (R4, R8): min-waves hints >2 make the allocator
// shrink below the ~200-reg weight working set and spill to scratch
// (R8: VGPR=64, 6.3 GB/dispatch scratch traffic). (256,2) = 124 VGPR, no spill.
__global__ __launch_bounds__(256, 2)
void lstm_fused(const float* __restrict__ x,
                const float* __restrict__ w1i, const float* __restrict__ w1h, const float* __restrict__ b1,
                const float* __restrict__ w2i, const float* __restrict__ w2h, const float* __restrict__ b2,
                const float* __restrict__ w3i, const float* __restrict__ w3h, const float* __restrict__ b3,
                const float* __restrict__ w4i, const float* __restrict__ w4h, const float* __restrict__ b4,
                const float* __restrict__ w5i, const float* __restrict__ w5h, const float* __restrict__ b5,
                const float* __restrict__ w6i, const float* __restrict__ w6h, const float* __restrict__ b6,
                const float* __restrict__ fc1w, const float* __restrict__ fc1b,
                const float* __restrict__ fc2w, const float* __restrict__ fc2b,
                float* __restrict__ out)
{
    const int lane  = threadIdx.x & 63;
    const int w     = threadIdx.x >> 6;     // wave in block (0..3)
    const int g8    = lane >> 3;            // 8-elem sub-index (0..7)
    const int r8    = lane & 7;
    const int base8 = lane & 56;            // 8-lane group base
    const int g16   = lane >> 4;            // epilogue 16-lane grouping
    const int r16   = lane & 15;
    const int eb0   = w * 8;                // first block-elem of this wave
    const int ebg8  = eb0 + g8;
    const long gelem0 = (long)blockIdx.x * 32 + eb0;

    // per-wave-owned LDS (block-elem 0..31) -> no __syncthreads
    __shared__ float h1s[32][32];
    __shared__ float h2s[32][8];
    __shared__ float h6s[32][68];
    __shared__ float accs[32][36];

    #pragma unroll
    for (int e=0;e<8;++e){
        if (lane<32) h1s[eb0+e][lane]=0.f;
        if (lane<8)  h2s[eb0+e][lane]=0.f;
    }

    // ---------------- weight preload (packed-pair, register-resident) ----
    // e1: even lane holds rows {i_u, g_u}; odd lane {f_u, o_u}; u=lane>>1
    const int  u1  = lane >> 1;
    const int  rA  = ((lane & 1) << 5) + u1;
    const int  rB  = 64 + rA;
    const bool evn = (lane & 1) == 0;
    v2f w1iA2[4], w1iB2[4], w1hA2[16], w1hB2[16];
    {
        #pragma unroll
        for (int q=0;q<2;++q){
            v4f va = *(const v4f*)(w1i + rA*8 + 4*q);
            v4f vb = *(const v4f*)(w1i + rB*8 + 4*q);
            w1iA2[2*q]=SVLO(va); w1iA2[2*q+1]=SVHI(va);
            w1iB2[2*q]=SVLO(vb); w1iB2[2*q+1]=SVHI(vb);
        }
        load_pairs32(w1h + rA*32, w1hA2);
        load_pairs32(w1h + rB*32, w1hB2);
    }
    const float bA_ = b1[rA], bB_ = b1[rB];

    // e2: lane owns row r2 (halves serve different elems)
    const int r2 = lane & 31;
    v2f w2i2[16], w2h2[4];
    {
        load_pairs32(w2i + r2*32, w2i2);
        v4f v0 = *(const v4f*)(w2h + r2*8);
        v4f v1 = *(const v4f*)(w2h + r2*8 + 4);
        w2h2[0]=SVLO(v0); w2h2[1]=SVHI(v0); w2h2[2]=SVLO(v1); w2h2[3]=SVHI(v1);
    }
    const float b2_ = b2[r2];
    const bool tg2 = ((r2>>3)==2);

    // e3/d3 rows on r34 = r8&3 (duplicated in both 4-lane subgroups)
    const int r34 = r8 & 3;
    float w3i_[8];
    {
        const float4* p = (const float4*)(w3i + r34*8);
        float4 v0=p[0], v1=p[1];
        w3i_[0]=v0.x;w3i_[1]=v0.y;w3i_[2]=v0.z;w3i_[3]=v0.w;
        w3i_[4]=v1.x;w3i_[5]=v1.y;w3i_[6]=v1.z;w3i_[7]=v1.w;
    }
    const float w3h_ = w3h[r34], b3_ = b3[r34];
    const bool tg3 = (r34==2);

    // d1/d2 rows on r8 (8 rows x 8 elems = full wave)
    const float w4i_ = w4i[r8], w4h0 = w4h[r8*2], w4h1 = w4h[r8*2+1], b4_ = b4[r8];
    const float w5i0 = w5i[r8*2], w5i1 = w5i[r8*2+1], w5h0 = w5h[r8*2], w5h1 = w5h[r8*2+1], b5_ = b5[r8];
    const bool tg45 = ((r8>>1)==2);
    const float w6i0 = w6i[r34*2], w6i1 = w6i[r34*2+1], w6h_ = w6h[r34], b6_ = b6[r34];

    // ---------------- states -------------------------------------------
    float c1e[8] = {0.f,0.f,0.f,0.f,0.f,0.f,0.f,0.f};
    float c2p[4] = {0.f,0.f,0.f,0.f};
    float c3=0.f, h3=0.f;
    float c4=0.f, h4a=0.f, h4b=0.f;
    float c5=0.f, h5a=0.f, h5b=0.f;
    float c6=0.f, h6=0.f;

    // ================= encoder loop (t < 48) ===========================
    for (int t=0; t<TSEQ; ++t){
        // ---- e1: 8 passes, shared packed weights ----
        #pragma unroll
        for (int e=0;e<8;++e){
            const float* xr = x + (size_t)(gelem0+e)*(TSEQ*8) + t*8;
            v4f xa = *(const v4f*)xr;
            v4f xb = *(const v4f*)(xr+4);
            v2f xp[4] = { SVLO(xa), SVHI(xa), SVLO(xb), SVHI(xb) };
            v2f h1p[16];
            load_pairs32(&h1s[eb0+e][0], h1p);

            v2f aq[2] = { (v2f){bA_,0.f}, (v2f){0.f,0.f} };
            v2f bq[2] = { (v2f){bB_,0.f}, (v2f){0.f,0.f} };
            #pragma unroll
            for (int j=0;j<4;++j){
                aq[j&1] = pkfma(w1iA2[j], xp[j], aq[j&1]);
                bq[j&1] = pkfma(w1iB2[j], xp[j], bq[j&1]);
            }
            #pragma unroll
            for (int k=0;k<16;++k){
                aq[k&1] = pkfma(w1hA2[k], h1p[k], aq[k&1]);
                bq[k&1] = pkfma(w1hB2[k], h1p[k], bq[k&1]);
            }
            const v2f as = aq[0] + aq[1];
            const v2f bs = bq[0] + bq[1];
            const float gA = as[0] + as[1];
            const float gB = bs[0] + bs[1];

            const float actA = sigm(gA);                 // i (even) / f (odd)
            const float sB   = sigm(evn ? 2.f*gB : gB);
            const float actB = evn ? 2.f*sB-1.f : sB;    // tanh g / sigm o
            const float pA = dppf<0xB1>(actA);           // xor1 via quad_perm
            const float pB = dppf<0xB1>(actB);
            const float iv = evn ? actA : pA;
            const float fv = evn ? pA   : actA;
            const float gv = evn ? actB : pB;
            const float ov = evn ? pB   : actB;
            c1e[e] = fv*c1e[e] + iv*gv;
            const float h1n = ov*tanhx(c1e[e]);
            if (evn) h1s[eb0+e][u1] = h1n;
        }

        // ---- e2: 4 passes x 2 elems ----
        #pragma unroll
        for (int p=0;p<4;++p){
            const int eb2 = eb0 + p*2 + (lane>>5);
            v2f h1p[16];
            load_pairs32(&h1s[eb2][0], h1p);
            v2f h2p[4];
            {
                v4f v0 = *(const v4f*)&h2s[eb2][0];
                v4f v1 = *(const v4f*)&h2s[eb2][4];
                h2p[0]=SVLO(v0); h2p[1]=SVHI(v0); h2p[2]=SVLO(v1); h2p[3]=SVHI(v1);
            }
            v2f qq[2] = { (v2f){b2_,0.f}, (v2f){0.f,0.f} };
            #pragma unroll
            for (int k=0;k<16;++k) qq[k&1] = pkfma(w2i2[k], h1p[k], qq[k&1]);
            #pragma unroll
            for (int k=0;k<4;++k)  qq[k&1] = pkfma(w2h2[k], h2p[k], qq[k&1]);
            const v2f qs = qq[0] + qq[1];
            const float g2 = qs[0] + qs[1];

            const float s2 = sigm(tg2 ? 2.f*g2 : g2);
            const float a2 = tg2 ? 2.f*s2-1.f : s2;
            const float f2  = dppf<0x128>(a2);           // xor8 via row_ror:8
            const float gv2 = __shfl_xor(a2, 16);
            const float o2  = __shfl_xor(a2, 24);
            c2p[p] = f2*c2p[p] + a2*gv2;           // valid r2<8
            const float h2n = o2*tanhx(c2p[p]);
            if (r2<8) h2s[eb2][r2] = h2n;
        }

        // ---- e3: 8 elems in 8-lane groups (rows duplicated in 4-subgroups)
        float h2g[8];
        {
            v4f v0 = *(const v4f*)&h2s[ebg8][0];
            v4f v1 = *(const v4f*)&h2s[ebg8][4];
            h2g[0]=v0[0];h2g[1]=v0[1];h2g[2]=v0[2];h2g[3]=v0[3];
            h2g[4]=v1[0];h2g[5]=v1[1];h2g[6]=v1[2];h2g[7]=v1[3];
        }
        float g3 = b3_ + w3h_*h3;
        #pragma unroll
        for (int j=0;j<8;++j) g3 += w3i_[j]*h2g[j];
        const float s3 = sigm(tg3 ? 2.f*g3 : g3);
        const float a3 = tg3 ? 2.f*s3-1.f : s3;
        const float e1x = dppf<0xB1>(a3);            // xor1
        const float e2x = dppf<0x4E>(a3);            // xor2
        const float e3x = dppf<0x1B>(a3);            // xor3
        c3 = e1x*c3 + a3*e2x;                      // valid r34==0
        h3 = __shfl(e3x*tanhx(c3), base8);
        const float din = h3;

        // ---- d1/d2/d3 + h6 store ----
        {
            const float g = b4_ + w4i_*din + w4h0*h4a + w4h1*h4b;
            const float s = sigm(tg45 ? 2.f*g : g);
            const float a = tg45 ? 2.f*s-1.f : s;
            const float y2 = dppf<0x4E>(a);          // xor2
            const float y4 = __shfl_xor(a, 4);
            const float y6 = __shfl_xor(a, 6);
            c4 = y2*c4 + a*y4;                     // valid r8<2
            const float hl = y6*tanhx(c4);
            h4a = __shfl(hl, base8);
            h4b = __shfl(hl, base8+1);
        }
        {
            const float g = b5_ + w5i0*h4a + w5i1*h4b + w5h0*h5a + w5h1*h5b;
            const float s = sigm(tg45 ? 2.f*g : g);
            const float a = tg45 ? 2.f*s-1.f : s;
            const float y2 = dppf<0x4E>(a);
            const float y4 = __shfl_xor(a, 4);
            const float y6 = __shfl_xor(a, 6);
            c5 = y2*c5 + a*y4;
            const float hl = y6*tanhx(c5);
            h5a = __shfl(hl, base8);
            h5b = __shfl(hl, base8+1);
        }
        {
            const float g = b6_ + w6i0*h5a + w6i1*h5b + w6h_*h6;
            const float s = sigm(tg3 ? 2.f*g : g);
            const float a = tg3 ? 2.f*s-1.f : s;
            const float z1 = dppf<0xB1>(a);
            const float z2 = dppf<0x4E>(a);
            const float z3 = dppf<0x1B>(a);
            c6 = z1*c6 + a*z2;                     // valid r34==0
            h6 = __shfl(z3*tanhx(c6), base8);
        }
        if (r8==0) h6s[ebg8][t] = h6;
    }

    // ================= decoder-only loop (t >= 48) =====================
    for (int t=TSEQ; t<TDEC; ++t){
        const float din = x[(size_t)(gelem0+g8)*(TSEQ*8) + (t-12)*8 + 4];
        {
            const float g = b4_ + w4i_*din + w4h0*h4a + w4h1*h4b;
            const float s = sigm(tg45 ? 2.f*g : g);
            const float a = tg45 ? 2.f*s-1.f : s;
            const float y2 = dppf<0x4E>(a);
            const float y4 = __shfl_xor(a, 4);
            const float y6 = __shfl_xor(a, 6);
            c4 = y2*c4 + a*y4;
            const float hl = y6*tanhx(c4);
            h4a = __shfl(hl, base8);
            h4b = __shfl(hl, base8+1);
        }
        {
            const float g = b5_ + w5i0*h4a + w5i1*h4b + w5h0*h5a + w5h1*h5b;
            const float s = sigm(tg45 ? 2.f*g : g);
            const float a = tg45 ? 2.f*s-1.f : s;
            const float y2 = dppf<0x4E>(a);
            const float y4 = __shfl_xor(a, 4);
            const float y6 = __shfl_xor(a, 6);
            c5 = y2*c5 + a*y4;
            const float hl = y6*tanhx(c5);
            h5a = __shfl(hl, base8);
            h5b = __shfl(hl, base8+1);
        }
        {
            const float g = b6_ + w6i0*h5a + w6i1*h5b + w6h_*h6;
            const float s = sigm(tg3 ? 2.f*g : g);
            const float a = tg3 ? 2.f*s-1.f : s;
            const float z1 = dppf<0xB1>(a);
            const float z2 = dppf<0x4E>(a);
            const float z3 = dppf<0x1B>(a);
            c6 = z1*c6 + a*z2;
            h6 = __shfl(z3*tanhx(c6), base8);
        }
        if (r8==0) h6s[ebg8][t] = h6;
    }

    // ================= epilogue: fc1/fc2, two 4-elem passes ============
    #pragma unroll
    for (int p=0;p<2;++p){
        const int ebgE = eb0 + p*4 + g16;
        {
            float a0 = fc1b[r16], a1 = fc1b[16+r16];
            const float* f0 = fc1w + r16*60;
            const float* f1 = fc1w + (16+r16)*60;
            #pragma unroll
            for (int q=0;q<15;++q){
                float4 hv = *reinterpret_cast<float4*>(&h6s[ebgE][4*q]);
                float4 u0 = *reinterpret_cast<const float4*>(f0 + 4*q);
                float4 u1v= *reinterpret_cast<const float4*>(f1 + 4*q);
                a0 += u0.x*hv.x + u0.y*hv.y + u0.z*hv.z + u0.w*hv.w;
                a1 += u1v.x*hv.x + u1v.y*hv.y + u1v.z*hv.z + u1v.w*hv.w;
            }
            accs[ebgE][r16]    = a0;
            accs[ebgE][16+r16] = a1;
        }
        if (r16 < 12){
            float o = fc2b[r16];
            const float* fr = fc2w + r16*32;
            #pragma unroll
            for (int q=0;q<8;++q){
                float4 av = *reinterpret_cast<float4*>(&accs[ebgE][4*q]);
                float4 wv = *reinterpret_cast<const float4*>(fr + 4*q);
                o += wv.x*av.x + wv.y*av.y + wv.z*av.z + wv.w*av.w;
            }
            out[(size_t)(gelem0 + p*4 + g16)*12 + r16] = o;
        }
    }
}

extern "C" void kernel_launch(void* const* d_in, const int* in_sizes, int n_in,
                              void* d_out, int out_size, void* d_ws, size_t ws_size,
                              hipStream_t stream)
{
    const float* x    = (const float*)d_in[0];
    const float* w1i  = (const float*)d_in[1];
    const float* w1h  = (const float*)d_in[2];
    const float* b1   = (const float*)d_in[3];
    const float* w2i  = (const float*)d_in[4];
    const float* w2h  = (const float*)d_in[5];
    const float* b2   = (const float*)d_in[6];
    const float* w3i  = (const float*)d_in[7];
    const float* w3h  = (const float*)d_in[8];
    const float* b3   = (const float*)d_in[9];
    const float* w4i  = (const float*)d_in[10];
    const float* w4h  = (const float*)d_in[11];
    const float* b4   = (const float*)d_in[12];
    const float* w5i  = (const float*)d_in[13];
    const float* w5h  = (const float*)d_in[14];
    const float* b5   = (const float*)d_in[15];
    const float* w6i  = (const float*)d_in[16];
    const float* w6h  = (const float*)d_in[17];
    const float* b6   = (const float*)d_in[18];
    const float* fc1w = (const float*)d_in[19];
    const float* fc1b = (const float*)d_in[20];
    const float* fc2w = (const float*)d_in[21];
    const float* fc2b = (const float*)d_in[22];

    // 8 elems/wave, 4 waves/block -> 32 elems/block -> 1024 blocks
    lstm_fused<<<dim3(32768/32), dim3(256), 0, stream>>>(
        x, w1i,w1h,b1, w2i,w2h,b2, w3i,w3h,b3,
        w4i,w4h,b4, w5i,w5h,b5, w6i,w6h,b6,
        fc1w,fc1b, fc2w,fc2b, (float*)d_out);
}